// Round 3
// baseline (469.776 us; speedup 1.0000x reference)
//
#include <hip/hip_runtime.h>
#include <hip/hip_bf16.h>
#include <stdint.h>

#define D_MODEL 1024
#define NH 16
#define DK 64
#define SEQ 2048
#define BATCH 2
#define NTOK (BATCH * SEQ)  // 4096

typedef __bf16 bf16;
typedef float f32x4 __attribute__((ext_vector_type(4)));
typedef __bf16 bf16x8 __attribute__((ext_vector_type(8)));
typedef __bf16 bf16x4 __attribute__((ext_vector_type(4)));

// 0.125 (1/sqrt(dk)) * log2(e): folded into Q so attn uses exp2 directly
#define QSCALE 0.18033687932432668f

__device__ __forceinline__ void gload_lds16(const void* g, void* l) {
  __builtin_amdgcn_global_load_lds(
      (const __attribute__((address_space(1))) void*)g,
      (__attribute__((address_space(3))) void*)l, 16, 0, 0);
}

// ---------------- prep kernels ----------------

__global__ void cast_x_kernel(const float* __restrict__ x, bf16* __restrict__ xb) {
  int i = blockIdx.x * 256 + threadIdx.x;
  float4 v = reinterpret_cast<const float4*>(x)[i];
  bf16x4 o;
  o[0] = (bf16)v.x; o[1] = (bf16)v.y; o[2] = (bf16)v.z; o[3] = (bf16)v.w;
  reinterpret_cast<bf16x4*>(xb)[i] = o;
}

// wt[j][k] = w_sel[k][j%1024], rows: [0,1024)=wq [1024,2048)=wk [2048,3072)=wv [3072,4096)=wo
__global__ void transpose_w_kernel(const float* __restrict__ wq, const float* __restrict__ wk,
                                   const float* __restrict__ wv, const float* __restrict__ wo,
                                   bf16* __restrict__ wt) {
  __shared__ float tile[32][33];
  const int jt = blockIdx.x;  // 0..127
  const int kt = blockIdx.y;  // 0..31
  const int tx = threadIdx.x & 31, ty = threadIdx.x >> 5;  // 32 x 8
  const int j0 = jt * 32;
  const int sel = j0 >> 10;
  const float* w = (sel == 0) ? wq : (sel == 1) ? wk : (sel == 2) ? wv : wo;
  const int jj0 = j0 & 1023;
#pragma unroll
  for (int i = 0; i < 4; ++i)
    tile[ty + i * 8][tx] = w[(size_t)(kt * 32 + ty + i * 8) * 1024 + jj0 + tx];
  __syncthreads();
#pragma unroll
  for (int i = 0; i < 4; ++i)
    wt[(size_t)(j0 + ty + i * 8) * 1024 + kt * 32 + tx] = (bf16)tile[tx][ty + i * 8];
}

__global__ void pack_mask_kernel(const int* __restrict__ mask, unsigned long long* __restrict__ bits) {
  int gt = blockIdx.x * 256 + threadIdx.x;
  int wid = gt >> 6;
  int l = gt & 63;
  int m = mask[(size_t)wid * 64 + l];
  unsigned long long b = __ballot(m != 0);
  if (l == 0) bits[wid] = b;
}

// ---------------- GEMM: C = A (MxK) * Bt^T (Bt is NxK row-major) ----------------
// MODE 0: QKV epilogue (q scaled by QSCALE; q/k token-major bf16, v transposed per-head bf16)
// MODE 1: f32 output + bias
template <int MODE>
__global__ __launch_bounds__(256) void gemm_bt(
    const bf16* __restrict__ A, const bf16* __restrict__ Bt,
    const float* __restrict__ b0, const float* __restrict__ b1, const float* __restrict__ b2,
    bf16* __restrict__ out_q, bf16* __restrict__ out_k, bf16* __restrict__ out_vt,
    float* __restrict__ out_f) {
  __shared__ __align__(16) bf16 As[128 * 32];
  __shared__ __align__(16) bf16 Bs[128 * 32];
  const int tid = threadIdx.x;
  const int w = tid >> 6, l = tid & 63;
  const int wr = w >> 1, wc = w & 1;
  const int m0 = blockIdx.y * 128, n0 = blockIdx.x * 128;
  f32x4 acc[4][4] = {};
  const int lrow = l >> 2;       // 0..15
  const int lc8 = (l & 3) * 8;   // element col of the 16B chunk
  char* AsB = (char*)As;
  char* BsB = (char*)Bs;

  for (int k0 = 0; k0 < 1024; k0 += 32) {
#pragma unroll
    for (int is = 0; is < 2; ++is) {
      int arow = m0 + is * 64 + w * 16 + lrow;
      gload_lds16(A + (size_t)arow * 1024 + k0 + lc8, AsB + is * 4096 + w * 1024);
      int brow = n0 + is * 64 + w * 16 + lrow;
      gload_lds16(Bt + (size_t)brow * 1024 + k0 + lc8, BsB + is * 4096 + w * 1024);
    }
    __syncthreads();
    bf16x8 af[4], bfr[4];
#pragma unroll
    for (int m = 0; m < 4; ++m)
      af[m] = *reinterpret_cast<const bf16x8*>(As + (wr * 64 + m * 16 + (l & 15)) * 32 + (l >> 4) * 8);
#pragma unroll
    for (int n = 0; n < 4; ++n)
      bfr[n] = *reinterpret_cast<const bf16x8*>(Bs + (wc * 64 + n * 16 + (l & 15)) * 32 + (l >> 4) * 8);
#pragma unroll
    for (int m = 0; m < 4; ++m)
#pragma unroll
      for (int n = 0; n < 4; ++n)
        acc[m][n] = __builtin_amdgcn_mfma_f32_16x16x32_bf16(af[m], bfr[n], acc[m][n], 0, 0, 0);
    __syncthreads();
  }

#pragma unroll
  for (int m = 0; m < 4; ++m) {
    int ib = m0 + wr * 64 + m * 16 + 4 * (l >> 4);
#pragma unroll
    for (int n = 0; n < 4; ++n) {
      int j = n0 + wc * 64 + n * 16 + (l & 15);
      if (MODE == 1) {
        float bias = b0[j];
#pragma unroll
        for (int r = 0; r < 4; ++r)
          out_f[(size_t)(ib + r) * 1024 + j] = acc[m][n][r] + bias;
      } else {
        int sel = j >> 10, jj = j & 1023;
        const float* bp = (sel == 0) ? b0 : (sel == 1) ? b1 : b2;
        float bias = bp[jj];
        if (sel == 0) {
#pragma unroll
          for (int r = 0; r < 4; ++r)
            out_q[(size_t)(ib + r) * 1024 + jj] = (bf16)((acc[m][n][r] + bias) * QSCALE);
        } else if (sel == 1) {
#pragma unroll
          for (int r = 0; r < 4; ++r)
            out_k[(size_t)(ib + r) * 1024 + jj] = (bf16)(acc[m][n][r] + bias);
        } else {
          int hh = jj >> 6, dd = jj & 63;
          int bb = ib >> 11, ss = ib & 2047;
          bf16x4 v;
#pragma unroll
          for (int r = 0; r < 4; ++r) v[r] = (bf16)(acc[m][n][r] + bias);
          *reinterpret_cast<bf16x4*>(out_vt + ((size_t)(bb * NH + hh) * DK + dd) * SEQ + ss) = v;
        }
      }
    }
  }
}

// ---------------- flash attention ----------------
// grid: (32 q-tiles of 64, NH, BATCH) = 1024 blocks, block 128 (2 waves x 32 q-rows)
// K/V staged with XOR-swizzled source (chunk ^= row&7), linear LDS dest; reads swizzled.
// 2-phase double-buffered staging with counted vmcnt + raw s_barrier.
__global__ __launch_bounds__(128) void attn_kernel(
    const bf16* __restrict__ qb, const bf16* __restrict__ kb,
    const bf16* __restrict__ vt, const unsigned long long* __restrict__ mbits,
    bf16* __restrict__ ob) {
  __shared__ __align__(16) bf16 Kbuf[2][64 * 64];  // [key][d] swizzled
  __shared__ __align__(16) bf16 Vbuf[2][64 * 64];  // [d][key] swizzled
  __shared__ __align__(16) bf16 Ps[2][32 * 64];    // per-wave [q][key] swizzled
  const int tid = threadIdx.x;
  const int w = tid >> 6, l = tid & 63;
  const int qt = blockIdx.x, h = blockIdx.y, b = blockIdx.z;
  const int q0 = qt * 64 + w * 32;
  const int tok0 = b * SEQ + q0;

  // Q fragments in registers (Q pre-scaled by QSCALE in the GEMM epilogue)
  bf16x8 qf[2][2];
#pragma unroll
  for (int m = 0; m < 2; ++m)
#pragma unroll
    for (int kk = 0; kk < 2; ++kk)
      qf[m][kk] = *reinterpret_cast<const bf16x8*>(
          qb + (size_t)(tok0 + m * 16 + (l & 15)) * 1024 + h * 64 + kk * 32 + (l >> 4) * 8);

  float mprev[2][4], lsum[2][4];
  f32x4 oacc[2][4] = {};
#pragma unroll
  for (int m = 0; m < 2; ++m)
#pragma unroll
    for (int r = 0; r < 4; ++r) { mprev[m][r] = -INFINITY; lsum[m][r] = 0.f; }

  const int lr = l >> 3;                 // staging row within 8-row group
  const int swz = ((l & 7) ^ lr) * 8;    // pre-swizzled source chunk (elements)
  const bf16* ksrc = kb + (size_t)(b * SEQ) * 1024 + h * 64;
  const bf16* vsrc = vt + (size_t)(b * NH + h) * DK * SEQ;

  auto STAGE = [&](int buf, int kt) {
#pragma unroll
    for (int i = 0; i < 4; ++i) {
      int row = i * 16 + w * 8 + lr;
      gload_lds16(ksrc + (size_t)(kt * 64 + row) * 1024 + swz, Kbuf[buf] + (i * 16 + w * 8) * 64);
      gload_lds16(vsrc + (size_t)row * SEQ + kt * 64 + swz, Vbuf[buf] + (i * 16 + w * 8) * 64);
    }
  };

  auto COMPUTE = [&](int buf, int kt) {
    const bf16* Kb = Kbuf[buf];
    const bf16* Vb = Vbuf[buf];
    // S = Q K^T  (32 q x 64 keys per wave)
    f32x4 sa[2][4] = {};
#pragma unroll
    for (int kk = 0; kk < 2; ++kk) {
      bf16x8 kf[4];
#pragma unroll
      for (int n = 0; n < 4; ++n) {
        int rr = n * 16 + (l & 15);
        kf[n] = *reinterpret_cast<const bf16x8*>(Kb + rr * 64 + (((kk * 4 + (l >> 4)) ^ (rr & 7)) << 3));
      }
#pragma unroll
      for (int m = 0; m < 2; ++m)
#pragma unroll
        for (int n = 0; n < 4; ++n)
          sa[m][n] = __builtin_amdgcn_mfma_f32_16x16x32_bf16(qf[m][kk], kf[n], sa[m][n], 0, 0, 0);
    }

    // masked online softmax (log2 domain; scores already scaled by QSCALE)
#pragma unroll
    for (int m = 0; m < 2; ++m) {
#pragma unroll
      for (int r = 0; r < 4; ++r) {
        int prow = m * 16 + 4 * (l >> 4) + r;
        int qg = q0 + prow;
        unsigned long long mw = mbits[(size_t)(b * SEQ + qg) * 32 + kt];
        unsigned long long sh = mw >> (l & 15);
        unsigned int blo = (unsigned int)sh, bhi = (unsigned int)(sh >> 32);
        float sv[4];
        sv[0] = (blo & 1u) ? sa[m][0][r] : -1e9f;
        sv[1] = (blo & 0x10000u) ? sa[m][1][r] : -1e9f;
        sv[2] = (bhi & 1u) ? sa[m][2][r] : -1e9f;
        sv[3] = (bhi & 0x10000u) ? sa[m][3][r] : -1e9f;
        float mx = fmaxf(fmaxf(sv[0], sv[1]), fmaxf(sv[2], sv[3]));
        mx = fmaxf(mx, __shfl_xor(mx, 1));
        mx = fmaxf(mx, __shfl_xor(mx, 2));
        mx = fmaxf(mx, __shfl_xor(mx, 4));
        mx = fmaxf(mx, __shfl_xor(mx, 8));
        float mnew = fmaxf(mprev[m][r], mx);
        float psum = 0.f;
#pragma unroll
        for (int n = 0; n < 4; ++n) {
          float p = __builtin_amdgcn_exp2f(sv[n] - mnew);
          psum += p;
          int col = n * 16 + (l & 15);
          Ps[w][prow * 64 + (((col >> 3) ^ (prow & 7)) << 3) + (col & 7)] = (bf16)p;
        }
        psum += __shfl_xor(psum, 1);
        psum += __shfl_xor(psum, 2);
        psum += __shfl_xor(psum, 4);
        psum += __shfl_xor(psum, 8);
        if (mnew > mprev[m][r]) {  // defer-rescale: skip when running max unchanged
          float alpha = __builtin_amdgcn_exp2f(mprev[m][r] - mnew);
          lsum[m][r] = lsum[m][r] * alpha + psum;
          mprev[m][r] = mnew;
#pragma unroll
          for (int dn = 0; dn < 4; ++dn) oacc[m][dn][r] *= alpha;
        } else {
          lsum[m][r] += psum;
        }
      }
    }

    // O += P * V
#pragma unroll
    for (int kk = 0; kk < 2; ++kk) {
      bf16x8 pa[2], vf[4];
      int c = kk * 4 + (l >> 4);
#pragma unroll
      for (int m = 0; m < 2; ++m) {
        int rr = m * 16 + (l & 15);
        pa[m] = *reinterpret_cast<const bf16x8*>(Ps[w] + rr * 64 + ((c ^ (rr & 7)) << 3));
      }
#pragma unroll
      for (int dn = 0; dn < 4; ++dn) {
        int rr = dn * 16 + (l & 15);
        vf[dn] = *reinterpret_cast<const bf16x8*>(Vb + rr * 64 + ((c ^ (rr & 7)) << 3));
      }
#pragma unroll
      for (int m = 0; m < 2; ++m)
#pragma unroll
        for (int dn = 0; dn < 4; ++dn)
          oacc[m][dn] = __builtin_amdgcn_mfma_f32_16x16x32_bf16(pa[m], vf[dn], oacc[m][dn], 0, 0, 0);
    }
  };

  STAGE(0, 0);
  for (int kt = 0; kt < 31; ++kt) {
    STAGE((kt + 1) & 1, kt + 1);
    __builtin_amdgcn_sched_barrier(0);
    asm volatile("s_waitcnt vmcnt(8)" ::: "memory");
    __builtin_amdgcn_s_barrier();
    __builtin_amdgcn_sched_barrier(0);
    COMPUTE(kt & 1, kt);
    __builtin_amdgcn_s_barrier();  // protect buf before next STAGE overwrites
  }
  __builtin_amdgcn_sched_barrier(0);
  asm volatile("s_waitcnt vmcnt(0)" ::: "memory");
  __builtin_amdgcn_s_barrier();
  __builtin_amdgcn_sched_barrier(0);
  COMPUTE(1, 31);

  // epilogue: normalize and store bf16 token-major
#pragma unroll
  for (int m = 0; m < 2; ++m)
#pragma unroll
    for (int r = 0; r < 4; ++r) {
      float inv = 1.f / lsum[m][r];
      int tok = tok0 + m * 16 + 4 * (l >> 4) + r;
#pragma unroll
      for (int dn = 0; dn < 4; ++dn)
        ob[(size_t)tok * 1024 + h * 64 + dn * 16 + (l & 15)] = (bf16)(oacc[m][dn][r] * inv);
    }
}

// ---------------- launch ----------------
extern "C" void kernel_launch(void* const* d_in, const int* in_sizes, int n_in,
                              void* d_out, int out_size, void* d_ws, size_t ws_size,
                              hipStream_t stream) {
  const float* x = (const float*)d_in[0];
  const int* mask = (const int*)d_in[1];
  const float* wq = (const float*)d_in[2];
  const float* bq = (const float*)d_in[3];
  const float* wk = (const float*)d_in[4];
  const float* bk = (const float*)d_in[5];
  const float* wv = (const float*)d_in[6];
  const float* bv = (const float*)d_in[7];
  const float* wo = (const float*)d_in[8];
  const float* bo = (const float*)d_in[9];
  float* out = (float*)d_out;

  char* ws = (char*)d_ws;
  bf16* xb = (bf16*)(ws + (size_t)0);             // 8 MB  [4096][1024]
  bf16* wt = (bf16*)(ws + ((size_t)8 << 20));     // 8 MB  [4096][1024] transposed weights
  bf16* qb = (bf16*)(ws + ((size_t)16 << 20));    // 8 MB  token-major (pre-scaled)
  bf16* kb = (bf16*)(ws + ((size_t)24 << 20));    // 8 MB  token-major
  bf16* vtb = (bf16*)(ws + ((size_t)32 << 20));   // 8 MB  [b][h][d][s]
  bf16* ob = (bf16*)(ws + ((size_t)40 << 20));    // 8 MB  token-major
  unsigned long long* mbits = (unsigned long long*)(ws + ((size_t)48 << 20));  // 1 MB

  cast_x_kernel<<<4096, 256, 0, stream>>>(x, xb);
  transpose_w_kernel<<<dim3(128, 32), 256, 0, stream>>>(wq, wk, wv, wo, wt);
  pack_mask_kernel<<<32768, 256, 0, stream>>>(mask, mbits);
  gemm_bt<0><<<dim3(24, 32), 256, 0, stream>>>(xb, wt, bq, bk, bv, qb, kb, vtb, nullptr);
  attn_kernel<<<dim3(32, NH, BATCH), 128, 0, stream>>>(qb, kb, vtb, mbits, ob);
  gemm_bt<1><<<dim3(8, 32), 256, 0, stream>>>(ob, wt + (size_t)3072 * 1024, bo, nullptr, nullptr,
                                              nullptr, nullptr, nullptr, out);
}

// Round 4
// 295.717 us; speedup vs baseline: 1.5886x; 1.5886x over previous
//
#include <hip/hip_runtime.h>
#include <hip/hip_bf16.h>
#include <stdint.h>

#define D_MODEL 1024
#define NH 16
#define DK 64
#define SEQ 2048
#define BATCH 2
#define NTOK (BATCH * SEQ)  // 4096

typedef __bf16 bf16;
typedef float f32x4 __attribute__((ext_vector_type(4)));
typedef __bf16 bf16x8 __attribute__((ext_vector_type(8)));
typedef __bf16 bf16x4 __attribute__((ext_vector_type(4)));

// 0.125 (1/sqrt(dk)) * log2(e): folded into Q so attn uses exp2 directly
#define QSCALE 0.18033687932432668f

__device__ __forceinline__ void gload_lds16(const void* g, void* l) {
  __builtin_amdgcn_global_load_lds(
      (const __attribute__((address_space(1))) void*)g,
      (__attribute__((address_space(3))) void*)l, 16, 0, 0);
}

// ---------------- prep kernels ----------------

__global__ void cast_x_kernel(const float* __restrict__ x, bf16* __restrict__ xb) {
  int i = blockIdx.x * 256 + threadIdx.x;
  float4 v = reinterpret_cast<const float4*>(x)[i];
  bf16x4 o;
  o[0] = (bf16)v.x; o[1] = (bf16)v.y; o[2] = (bf16)v.z; o[3] = (bf16)v.w;
  reinterpret_cast<bf16x4*>(xb)[i] = o;
}

// wt[j][k] = w_sel[k][j%1024], rows: [0,1024)=wq [1024,2048)=wk [2048,3072)=wv [3072,4096)=wo
__global__ void transpose_w_kernel(const float* __restrict__ wq, const float* __restrict__ wk,
                                   const float* __restrict__ wv, const float* __restrict__ wo,
                                   bf16* __restrict__ wt) {
  __shared__ float tile[32][33];
  const int jt = blockIdx.x;  // 0..127
  const int kt = blockIdx.y;  // 0..31
  const int tx = threadIdx.x & 31, ty = threadIdx.x >> 5;  // 32 x 8
  const int j0 = jt * 32;
  const int sel = j0 >> 10;
  const float* w = (sel == 0) ? wq : (sel == 1) ? wk : (sel == 2) ? wv : wo;
  const int jj0 = j0 & 1023;
#pragma unroll
  for (int i = 0; i < 4; ++i)
    tile[ty + i * 8][tx] = w[(size_t)(kt * 32 + ty + i * 8) * 1024 + jj0 + tx];
  __syncthreads();
#pragma unroll
  for (int i = 0; i < 4; ++i)
    wt[(size_t)(j0 + ty + i * 8) * 1024 + kt * 32 + tx] = (bf16)tile[tx][ty + i * 8];
}

__global__ void pack_mask_kernel(const int* __restrict__ mask, unsigned long long* __restrict__ bits) {
  int gt = blockIdx.x * 256 + threadIdx.x;
  int wid = gt >> 6;
  int l = gt & 63;
  int m = mask[(size_t)wid * 64 + l];
  unsigned long long b = __ballot(m != 0);
  if (l == 0) bits[wid] = b;
}

// ---------------- GEMM: C = A (MxK) * Bt^T (Bt is NxK row-major) ----------------
// MODE 0: QKV epilogue (q scaled by QSCALE; q/k token-major bf16, v transposed per-head bf16)
// MODE 1: f32 output + bias
template <int MODE>
__global__ __launch_bounds__(256) void gemm_bt(
    const bf16* __restrict__ A, const bf16* __restrict__ Bt,
    const float* __restrict__ b0, const float* __restrict__ b1, const float* __restrict__ b2,
    bf16* __restrict__ out_q, bf16* __restrict__ out_k, bf16* __restrict__ out_vt,
    float* __restrict__ out_f) {
  __shared__ __align__(16) bf16 As[128 * 32];
  __shared__ __align__(16) bf16 Bs[128 * 32];
  const int tid = threadIdx.x;
  const int w = tid >> 6, l = tid & 63;
  const int wr = w >> 1, wc = w & 1;
  const int m0 = blockIdx.y * 128, n0 = blockIdx.x * 128;
  f32x4 acc[4][4] = {};
  const int lrow = l >> 2;       // 0..15
  const int lc8 = (l & 3) * 8;   // element col of the 16B chunk
  char* AsB = (char*)As;
  char* BsB = (char*)Bs;

  for (int k0 = 0; k0 < 1024; k0 += 32) {
#pragma unroll
    for (int is = 0; is < 2; ++is) {
      int arow = m0 + is * 64 + w * 16 + lrow;
      gload_lds16(A + (size_t)arow * 1024 + k0 + lc8, AsB + is * 4096 + w * 1024);
      int brow = n0 + is * 64 + w * 16 + lrow;
      gload_lds16(Bt + (size_t)brow * 1024 + k0 + lc8, BsB + is * 4096 + w * 1024);
    }
    __syncthreads();
    bf16x8 af[4], bfr[4];
#pragma unroll
    for (int m = 0; m < 4; ++m)
      af[m] = *reinterpret_cast<const bf16x8*>(As + (wr * 64 + m * 16 + (l & 15)) * 32 + (l >> 4) * 8);
#pragma unroll
    for (int n = 0; n < 4; ++n)
      bfr[n] = *reinterpret_cast<const bf16x8*>(Bs + (wc * 64 + n * 16 + (l & 15)) * 32 + (l >> 4) * 8);
#pragma unroll
    for (int m = 0; m < 4; ++m)
#pragma unroll
      for (int n = 0; n < 4; ++n)
        acc[m][n] = __builtin_amdgcn_mfma_f32_16x16x32_bf16(af[m], bfr[n], acc[m][n], 0, 0, 0);
    __syncthreads();
  }

#pragma unroll
  for (int m = 0; m < 4; ++m) {
    int ib = m0 + wr * 64 + m * 16 + 4 * (l >> 4);
#pragma unroll
    for (int n = 0; n < 4; ++n) {
      int j = n0 + wc * 64 + n * 16 + (l & 15);
      if (MODE == 1) {
        float bias = b0[j];
#pragma unroll
        for (int r = 0; r < 4; ++r)
          out_f[(size_t)(ib + r) * 1024 + j] = acc[m][n][r] + bias;
      } else {
        int sel = j >> 10, jj = j & 1023;
        const float* bp = (sel == 0) ? b0 : (sel == 1) ? b1 : b2;
        float bias = bp[jj];
        if (sel == 0) {
#pragma unroll
          for (int r = 0; r < 4; ++r)
            out_q[(size_t)(ib + r) * 1024 + jj] = (bf16)((acc[m][n][r] + bias) * QSCALE);
        } else if (sel == 1) {
#pragma unroll
          for (int r = 0; r < 4; ++r)
            out_k[(size_t)(ib + r) * 1024 + jj] = (bf16)(acc[m][n][r] + bias);
        } else {
          int hh = jj >> 6, dd = jj & 63;
          int bb = ib >> 11, ss = ib & 2047;
          bf16x4 v;
#pragma unroll
          for (int r = 0; r < 4; ++r) v[r] = (bf16)(acc[m][n][r] + bias);
          *reinterpret_cast<bf16x4*>(out_vt + ((size_t)(bb * NH + hh) * DK + dd) * SEQ + ss) = v;
        }
      }
    }
  }
}

// ---------------- flash attention ----------------
// grid: (32 q-tiles of 64, NH, BATCH) = 1024 blocks, block 256 (4 waves x 16 q-rows)
// LDS 24KB -> 4 blocks/CU (grid-limited), 16 waves/CU.
// K/V staged with XOR-swizzled source chunk (^= row&7), linear LDS dest; reads swizzled.
__global__ __launch_bounds__(256, 4) void attn_kernel(
    const bf16* __restrict__ qb, const bf16* __restrict__ kb,
    const bf16* __restrict__ vt, const unsigned long long* __restrict__ mbits,
    bf16* __restrict__ ob) {
  __shared__ __align__(16) bf16 Ks[64 * 64];     // [key][d] swizzled
  __shared__ __align__(16) bf16 Vs[64 * 64];     // [d][key] swizzled
  __shared__ __align__(16) bf16 Ps[4][16 * 64];  // per-wave [q][key] swizzled
  const int tid = threadIdx.x;
  const int w = tid >> 6, l = tid & 63;
  const int qt = blockIdx.x, h = blockIdx.y, b = blockIdx.z;
  const int q0 = qt * 64;
  const int qrow = q0 + w * 16;          // this wave's first q-row
  const int tok0 = b * SEQ + qrow;

  // Q fragments (Q pre-scaled by QSCALE in GEMM epilogue): [kk]
  bf16x8 qf[2];
#pragma unroll
  for (int kk = 0; kk < 2; ++kk)
    qf[kk] = *reinterpret_cast<const bf16x8*>(
        qb + (size_t)(tok0 + (l & 15)) * 1024 + h * 64 + kk * 32 + (l >> 4) * 8);

  float mprev[4], lsum[4];
  f32x4 oacc[4] = {};
#pragma unroll
  for (int r = 0; r < 4; ++r) { mprev[r] = -INFINITY; lsum[r] = 0.f; }

  const int swz = ((l & 7) ^ (l >> 3)) * 8;  // pre-swizzled source chunk (elements)
  const bf16* ksrc = kb + (size_t)(b * SEQ) * 1024 + h * 64;
  const bf16* vsrc = vt + (size_t)(b * NH + h) * DK * SEQ;
  const unsigned long long* mrow = mbits + ((size_t)(b * SEQ + qrow + 4 * (l >> 4)) << 5);

  for (int kt = 0; kt < 32; ++kt) {
    // mask-word prefetch: completes under staging latency
    unsigned long long mw[4];
#pragma unroll
    for (int r = 0; r < 4; ++r) mw[r] = mrow[(size_t)(r << 5) + kt];

    // stage K,V tile (2 issues each: 32 rows x 128B per issue)
#pragma unroll
    for (int i = 0; i < 2; ++i) {
      int row = i * 32 + w * 8 + (l >> 3);
      gload_lds16(ksrc + (size_t)(kt * 64 + row) * 1024 + swz,
                  (char*)Ks + i * 4096 + w * 1024 + (l & 63) * 16 - (l & 63) * 16 + w * 0 + (size_t)0 + ((l * 16) & 1023));
      gload_lds16(vsrc + (size_t)row * SEQ + kt * 64 + swz,
                  (char*)Vs + i * 4096 + w * 1024 + ((l * 16) & 1023));
    }
    __syncthreads();

    // S = Q K^T (16 q x 64 keys per wave)
    f32x4 sa[4] = {};
#pragma unroll
    for (int kk = 0; kk < 2; ++kk) {
      bf16x8 kf[4];
      int c = kk * 4 + (l >> 4);
#pragma unroll
      for (int n = 0; n < 4; ++n) {
        int rr = n * 16 + (l & 15);
        kf[n] = *reinterpret_cast<const bf16x8*>(Ks + rr * 64 + ((c ^ (rr & 7)) << 3));
      }
#pragma unroll
      for (int n = 0; n < 4; ++n)
        sa[n] = __builtin_amdgcn_mfma_f32_16x16x32_bf16(qf[kk], kf[n], sa[n], 0, 0, 0);
    }

    // masked online softmax (log2 domain)
#pragma unroll
    for (int r = 0; r < 4; ++r) {
      int prow = 4 * (l >> 4) + r;
      unsigned long long sh = mw[r] >> (l & 15);
      unsigned int blo = (unsigned int)sh, bhi = (unsigned int)(sh >> 32);
      float sv[4];
      sv[0] = (blo & 1u) ? sa[0][r] : -1e9f;
      sv[1] = (blo & 0x10000u) ? sa[1][r] : -1e9f;
      sv[2] = (bhi & 1u) ? sa[2][r] : -1e9f;
      sv[3] = (bhi & 0x10000u) ? sa[3][r] : -1e9f;
      float mx = fmaxf(fmaxf(sv[0], sv[1]), fmaxf(sv[2], sv[3]));
      mx = fmaxf(mx, __shfl_xor(mx, 1));
      mx = fmaxf(mx, __shfl_xor(mx, 2));
      mx = fmaxf(mx, __shfl_xor(mx, 4));
      mx = fmaxf(mx, __shfl_xor(mx, 8));
      float mnew = fmaxf(mprev[r], mx);
      float psum = 0.f;
#pragma unroll
      for (int n = 0; n < 4; ++n) {
        float p = __builtin_amdgcn_exp2f(sv[n] - mnew);
        psum += p;
        int col = n * 16 + (l & 15);
        Ps[w][prow * 64 + ((((col >> 3)) ^ (prow & 7)) << 3) + (col & 7)] = (bf16)p;
      }
      psum += __shfl_xor(psum, 1);
      psum += __shfl_xor(psum, 2);
      psum += __shfl_xor(psum, 4);
      psum += __shfl_xor(psum, 8);
      float alpha = __builtin_amdgcn_exp2f(mprev[r] - mnew);
      mprev[r] = mnew;
      lsum[r] = lsum[r] * alpha + psum;
#pragma unroll
      for (int dn = 0; dn < 4; ++dn) oacc[dn][r] *= alpha;
    }

    // O += P * V
#pragma unroll
    for (int kk = 0; kk < 2; ++kk) {
      int c = kk * 4 + (l >> 4);
      bf16x8 pa, vf[4];
      {
        int rr = l & 15;
        pa = *reinterpret_cast<const bf16x8*>(Ps[w] + rr * 64 + ((c ^ (rr & 7)) << 3));
      }
#pragma unroll
      for (int dn = 0; dn < 4; ++dn) {
        int rr = dn * 16 + (l & 15);
        vf[dn] = *reinterpret_cast<const bf16x8*>(Vs + rr * 64 + ((c ^ (rr & 7)) << 3));
      }
#pragma unroll
      for (int dn = 0; dn < 4; ++dn)
        oacc[dn] = __builtin_amdgcn_mfma_f32_16x16x32_bf16(pa, vf[dn], oacc[dn], 0, 0, 0);
    }
    __syncthreads();
  }

  // epilogue: normalize and store bf16 token-major
#pragma unroll
  for (int r = 0; r < 4; ++r) {
    float inv = 1.f / lsum[r];
    int tok = tok0 + 4 * (l >> 4) + r;
#pragma unroll
    for (int dn = 0; dn < 4; ++dn)
      ob[(size_t)tok * 1024 + h * 64 + dn * 16 + (l & 15)] = (bf16)(oacc[dn][r] * inv);
  }
}

// ---------------- launch ----------------
extern "C" void kernel_launch(void* const* d_in, const int* in_sizes, int n_in,
                              void* d_out, int out_size, void* d_ws, size_t ws_size,
                              hipStream_t stream) {
  const float* x = (const float*)d_in[0];
  const int* mask = (const int*)d_in[1];
  const float* wq = (const float*)d_in[2];
  const float* bq = (const float*)d_in[3];
  const float* wk = (const float*)d_in[4];
  const float* bk = (const float*)d_in[5];
  const float* wv = (const float*)d_in[6];
  const float* bv = (const float*)d_in[7];
  const float* wo = (const float*)d_in[8];
  const float* bo = (const float*)d_in[9];
  float* out = (float*)d_out;

  char* ws = (char*)d_ws;
  bf16* xb = (bf16*)(ws + (size_t)0);             // 8 MB  [4096][1024]
  bf16* wt = (bf16*)(ws + ((size_t)8 << 20));     // 8 MB  [4096][1024] transposed weights
  bf16* qb = (bf16*)(ws + ((size_t)16 << 20));    // 8 MB  token-major (pre-scaled)
  bf16* kb = (bf16*)(ws + ((size_t)24 << 20));    // 8 MB  token-major
  bf16* vtb = (bf16*)(ws + ((size_t)32 << 20));   // 8 MB  [b][h][d][s]
  bf16* ob = (bf16*)(ws + ((size_t)40 << 20));    // 8 MB  token-major
  unsigned long long* mbits = (unsigned long long*)(ws + ((size_t)48 << 20));  // 1 MB

  cast_x_kernel<<<4096, 256, 0, stream>>>(x, xb);
  transpose_w_kernel<<<dim3(128, 32), 256, 0, stream>>>(wq, wk, wv, wo, wt);
  pack_mask_kernel<<<32768, 256, 0, stream>>>(mask, mbits);
  gemm_bt<0><<<dim3(24, 32), 256, 0, stream>>>(xb, wt, bq, bk, bv, qb, kb, vtb, nullptr);
  attn_kernel<<<dim3(32, NH, BATCH), 256, 0, stream>>>(qb, kb, vtb, mbits, ob);
  gemm_bt<1><<<dim3(8, 32), 256, 0, stream>>>(ob, wt + (size_t)3072 * 1024, bo, nullptr, nullptr,
                                              nullptr, nullptr, nullptr, out);
}

// Round 6
// 255.258 us; speedup vs baseline: 1.8404x; 1.1585x over previous
//
#include <hip/hip_runtime.h>
#include <hip/hip_bf16.h>
#include <stdint.h>

#define D_MODEL 1024
#define NH 16
#define DK 64
#define SEQ 2048
#define BATCH 2
#define NTOK (BATCH * SEQ)  // 4096

typedef __bf16 bf16;
typedef float f32x4 __attribute__((ext_vector_type(4)));
typedef __bf16 bf16x8 __attribute__((ext_vector_type(8)));
typedef __bf16 bf16x4 __attribute__((ext_vector_type(4)));

// 0.125 (1/sqrt(dk)) * log2(e): folded into Q so attn uses exp2 directly
#define QSCALE 0.18033687932432668f

__device__ __forceinline__ void gload_lds16(const void* g, void* l) {
  __builtin_amdgcn_global_load_lds(
      (const __attribute__((address_space(1))) void*)g,
      (__attribute__((address_space(3))) void*)l, 16, 0, 0);
}

// ---------------- prep kernels ----------------

__global__ void cast_x_kernel(const float* __restrict__ x, bf16* __restrict__ xb) {
  int i = blockIdx.x * 256 + threadIdx.x;
  float4 v = reinterpret_cast<const float4*>(x)[i];
  bf16x4 o;
  o[0] = (bf16)v.x; o[1] = (bf16)v.y; o[2] = (bf16)v.z; o[3] = (bf16)v.w;
  reinterpret_cast<bf16x4*>(xb)[i] = o;
}

// wt[j][k] = w_sel[k][j%1024], rows: [0,1024)=wq [1024,2048)=wk [2048,3072)=wv [3072,4096)=wo
__global__ void transpose_w_kernel(const float* __restrict__ wq, const float* __restrict__ wk,
                                   const float* __restrict__ wv, const float* __restrict__ wo,
                                   bf16* __restrict__ wt) {
  __shared__ float tile[32][33];
  const int jt = blockIdx.x;  // 0..127
  const int kt = blockIdx.y;  // 0..31
  const int tx = threadIdx.x & 31, ty = threadIdx.x >> 5;  // 32 x 8
  const int j0 = jt * 32;
  const int sel = j0 >> 10;
  const float* w = (sel == 0) ? wq : (sel == 1) ? wk : (sel == 2) ? wv : wo;
  const int jj0 = j0 & 1023;
#pragma unroll
  for (int i = 0; i < 4; ++i)
    tile[ty + i * 8][tx] = w[(size_t)(kt * 32 + ty + i * 8) * 1024 + jj0 + tx];
  __syncthreads();
#pragma unroll
  for (int i = 0; i < 4; ++i)
    wt[(size_t)(j0 + ty + i * 8) * 1024 + kt * 32 + tx] = (bf16)tile[tx][ty + i * 8];
}

__global__ void pack_mask_kernel(const int* __restrict__ mask, unsigned long long* __restrict__ bits) {
  int gt = blockIdx.x * 256 + threadIdx.x;
  int wid = gt >> 6;
  int l = gt & 63;
  int m = mask[(size_t)wid * 64 + l];
  unsigned long long b = __ballot(m != 0);
  if (l == 0) bits[wid] = b;
}

// ---------------- QKV GEMM: C = A (MxK) * Bt^T (Bt is NxK row-major) ----------------
// epilogue: q scaled by QSCALE; q/k token-major bf16, v transposed per-head bf16
__global__ __launch_bounds__(256) void gemm_qkv(
    const bf16* __restrict__ A, const bf16* __restrict__ Bt,
    const float* __restrict__ b0, const float* __restrict__ b1, const float* __restrict__ b2,
    bf16* __restrict__ out_q, bf16* __restrict__ out_k, bf16* __restrict__ out_vt) {
  __shared__ __align__(16) bf16 As[128 * 32];
  __shared__ __align__(16) bf16 Bs[128 * 32];
  const int tid = threadIdx.x;
  const int w = tid >> 6, l = tid & 63;
  const int wr = w >> 1, wc = w & 1;
  const int m0 = blockIdx.y * 128, n0 = blockIdx.x * 128;
  f32x4 acc[4][4] = {};
  const int lrow = l >> 2;       // 0..15
  const int lc8 = (l & 3) * 8;   // element col of the 16B chunk
  char* AsB = (char*)As;
  char* BsB = (char*)Bs;

  for (int k0 = 0; k0 < 1024; k0 += 32) {
#pragma unroll
    for (int is = 0; is < 2; ++is) {
      int arow = m0 + is * 64 + w * 16 + lrow;
      gload_lds16(A + (size_t)arow * 1024 + k0 + lc8, AsB + is * 4096 + w * 1024);
      int brow = n0 + is * 64 + w * 16 + lrow;
      gload_lds16(Bt + (size_t)brow * 1024 + k0 + lc8, BsB + is * 4096 + w * 1024);
    }
    __syncthreads();
    bf16x8 af[4], bfr[4];
#pragma unroll
    for (int m = 0; m < 4; ++m)
      af[m] = *reinterpret_cast<const bf16x8*>(As + (wr * 64 + m * 16 + (l & 15)) * 32 + (l >> 4) * 8);
#pragma unroll
    for (int n = 0; n < 4; ++n)
      bfr[n] = *reinterpret_cast<const bf16x8*>(Bs + (wc * 64 + n * 16 + (l & 15)) * 32 + (l >> 4) * 8);
#pragma unroll
    for (int m = 0; m < 4; ++m)
#pragma unroll
      for (int n = 0; n < 4; ++n)
        acc[m][n] = __builtin_amdgcn_mfma_f32_16x16x32_bf16(af[m], bfr[n], acc[m][n], 0, 0, 0);
    __syncthreads();
  }

#pragma unroll
  for (int m = 0; m < 4; ++m) {
    int ib = m0 + wr * 64 + m * 16 + 4 * (l >> 4);
#pragma unroll
    for (int n = 0; n < 4; ++n) {
      int j = n0 + wc * 64 + n * 16 + (l & 15);
      int sel = j >> 10, jj = j & 1023;
      const float* bp = (sel == 0) ? b0 : (sel == 1) ? b1 : b2;
      float bias = bp[jj];
      if (sel == 0) {
#pragma unroll
        for (int r = 0; r < 4; ++r)
          out_q[(size_t)(ib + r) * 1024 + jj] = (bf16)((acc[m][n][r] + bias) * QSCALE);
      } else if (sel == 1) {
#pragma unroll
        for (int r = 0; r < 4; ++r)
          out_k[(size_t)(ib + r) * 1024 + jj] = (bf16)(acc[m][n][r] + bias);
      } else {
        int hh = jj >> 6, dd = jj & 63;
        int bb = ib >> 11, ss = ib & 2047;
        bf16x4 v;
#pragma unroll
        for (int r = 0; r < 4; ++r) v[r] = (bf16)(acc[m][n][r] + bias);
        *reinterpret_cast<bf16x4*>(out_vt + ((size_t)(bb * NH + hh) * DK + dd) * SEQ + ss) = v;
      }
    }
  }
}

// ---------------- out-proj GEMM: 64x64 tile for occupancy (grid 16x64 = 1024 blocks) ----------------
__global__ __launch_bounds__(256) void gemm_out(
    const bf16* __restrict__ A, const bf16* __restrict__ Bt,
    const float* __restrict__ bias, float* __restrict__ out) {
  __shared__ __align__(16) bf16 As[64 * 32];
  __shared__ __align__(16) bf16 Bs[64 * 32];
  const int tid = threadIdx.x;
  const int w = tid >> 6, l = tid & 63;
  const int wr = w >> 1, wc = w & 1;  // 2x2 waves, each 32x32 output
  const int m0 = blockIdx.y * 64, n0 = blockIdx.x * 64;
  f32x4 acc[2][2] = {};
  const int srow = w * 16 + (l >> 2);  // staging row this lane covers
  const int sc8 = (l & 3) * 8;

  for (int k0 = 0; k0 < 1024; k0 += 32) {
    gload_lds16(A + (size_t)(m0 + srow) * 1024 + k0 + sc8, (char*)As + w * 1024);
    gload_lds16(Bt + (size_t)(n0 + srow) * 1024 + k0 + sc8, (char*)Bs + w * 1024);
    __syncthreads();
    bf16x8 af[2], bfr[2];
#pragma unroll
    for (int m = 0; m < 2; ++m)
      af[m] = *reinterpret_cast<const bf16x8*>(As + (wr * 32 + m * 16 + (l & 15)) * 32 + (l >> 4) * 8);
#pragma unroll
    for (int n = 0; n < 2; ++n)
      bfr[n] = *reinterpret_cast<const bf16x8*>(Bs + (wc * 32 + n * 16 + (l & 15)) * 32 + (l >> 4) * 8);
#pragma unroll
    for (int m = 0; m < 2; ++m)
#pragma unroll
      for (int n = 0; n < 2; ++n)
        acc[m][n] = __builtin_amdgcn_mfma_f32_16x16x32_bf16(af[m], bfr[n], acc[m][n], 0, 0, 0);
    __syncthreads();
  }

#pragma unroll
  for (int m = 0; m < 2; ++m) {
    int ib = m0 + wr * 32 + m * 16 + 4 * (l >> 4);
#pragma unroll
    for (int n = 0; n < 2; ++n) {
      int j = n0 + wc * 32 + n * 16 + (l & 15);
      float bv = bias[j];
#pragma unroll
      for (int r = 0; r < 4; ++r)
        out[(size_t)(ib + r) * 1024 + j] = acc[m][n][r] + bv;
    }
  }
}

// ---------------- flash attention ----------------
// grid: (32 q-tiles of 64, NH, BATCH) = 1024 blocks, block 256 (4 waves x 16 q-rows).
// No-max softmax (scores bounded; masked -> exp2(-1e9)=0) + per-lane deferred sum:
// ZERO cross-lane ops in the K-loop. K/V XOR-swizzled (0 bank conflicts).
__global__ __launch_bounds__(256, 4) void attn_kernel(
    const bf16* __restrict__ qb, const bf16* __restrict__ kb,
    const bf16* __restrict__ vt, const unsigned long long* __restrict__ mbits,
    bf16* __restrict__ ob) {
  __shared__ __align__(16) bf16 Ks[64 * 64];     // [key][d] swizzled
  __shared__ __align__(16) bf16 Vs[64 * 64];     // [d][key] swizzled
  __shared__ __align__(16) bf16 Ps[4][16 * 64];  // per-wave [q][key] swizzled
  const int tid = threadIdx.x;
  const int w = tid >> 6, l = tid & 63;
  const int qt = blockIdx.x, h = blockIdx.y, b = blockIdx.z;
  const int q0 = qt * 64;
  const int qrow = q0 + w * 16;
  const int tok0 = b * SEQ + qrow;

  // Q fragments (pre-scaled by QSCALE in GEMM epilogue)
  bf16x8 qf[2];
#pragma unroll
  for (int kk = 0; kk < 2; ++kk)
    qf[kk] = *reinterpret_cast<const bf16x8*>(
        qb + (size_t)(tok0 + (l & 15)) * 1024 + h * 64 + kk * 32 + (l >> 4) * 8);

  float lsum[4] = {0.f, 0.f, 0.f, 0.f};
  f32x4 oacc[4] = {};

  const int swz = ((l & 7) ^ (l >> 3)) * 8;  // pre-swizzled source chunk (elements)
  const bf16* ksrc = kb + (size_t)(b * SEQ) * 1024 + h * 64;
  const bf16* vsrc = vt + (size_t)(b * NH + h) * DK * SEQ;
  const unsigned long long* mrow = mbits + ((size_t)(b * SEQ + qrow + 4 * (l >> 4)) << 5);
  char* KsB = (char*)Ks;
  char* VsB = (char*)Vs;

  for (int kt = 0; kt < 32; ++kt) {
    // mask-word prefetch: completes under staging latency
    unsigned long long mw[4];
#pragma unroll
    for (int r = 0; r < 4; ++r) mw[r] = mrow[(size_t)(r << 5) + kt];

    // stage K,V tile (wave-uniform LDS base; lane offset implicit)
#pragma unroll
    for (int i = 0; i < 2; ++i) {
      int row = i * 32 + w * 8 + (l >> 3);
      gload_lds16(ksrc + (size_t)(kt * 64 + row) * 1024 + swz, KsB + i * 4096 + w * 1024);
      gload_lds16(vsrc + (size_t)row * SEQ + kt * 64 + swz, VsB + i * 4096 + w * 1024);
    }
    __syncthreads();

    // S = Q K^T (16 q x 64 keys per wave)
    f32x4 sa[4] = {};
#pragma unroll
    for (int kk = 0; kk < 2; ++kk) {
      bf16x8 kf[4];
      int c = kk * 4 + (l >> 4);
#pragma unroll
      for (int n = 0; n < 4; ++n) {
        int rr = n * 16 + (l & 15);
        kf[n] = *reinterpret_cast<const bf16x8*>(Ks + rr * 64 + ((c ^ (rr & 7)) << 3));
      }
#pragma unroll
      for (int n = 0; n < 4; ++n)
        sa[n] = __builtin_amdgcn_mfma_f32_16x16x32_bf16(qf[kk], kf[n], sa[n], 0, 0, 0);
    }

    // masked no-max softmax: p = mask ? exp2(s) : 0; per-lane partial sums only
#pragma unroll
    for (int r = 0; r < 4; ++r) {
      int prow = 4 * (l >> 4) + r;
      unsigned long long sh = mw[r] >> (l & 15);
      unsigned int blo = (unsigned int)sh, bhi = (unsigned int)(sh >> 32);
      float p0 = (blo & 1u) ? __builtin_amdgcn_exp2f(sa[0][r]) : 0.f;
      float p1 = (blo & 0x10000u) ? __builtin_amdgcn_exp2f(sa[1][r]) : 0.f;
      float p2 = (bhi & 1u) ? __builtin_amdgcn_exp2f(sa[2][r]) : 0.f;
      float p3 = (bhi & 0x10000u) ? __builtin_amdgcn_exp2f(sa[3][r]) : 0.f;
      lsum[r] += (p0 + p1) + (p2 + p3);
      int colb = l & 7;
      int swzr = (prow & 7);
#pragma unroll
      for (int n = 0; n < 4; ++n) {
        int col = n * 16 + (l & 15);
        float p = (n == 0) ? p0 : (n == 1) ? p1 : (n == 2) ? p2 : p3;
        Ps[w][prow * 64 + (((col >> 3) ^ swzr) << 3) + colb] = (bf16)p;
      }
    }

    // O += P * V
#pragma unroll
    for (int kk = 0; kk < 2; ++kk) {
      int c = kk * 4 + (l >> 4);
      bf16x8 pa, vf[4];
      {
        int rr = l & 15;
        pa = *reinterpret_cast<const bf16x8*>(Ps[w] + rr * 64 + ((c ^ (rr & 7)) << 3));
      }
#pragma unroll
      for (int dn = 0; dn < 4; ++dn) {
        int rr = dn * 16 + (l & 15);
        vf[dn] = *reinterpret_cast<const bf16x8*>(Vs + rr * 64 + ((c ^ (rr & 7)) << 3));
      }
#pragma unroll
      for (int dn = 0; dn < 4; ++dn)
        oacc[dn] = __builtin_amdgcn_mfma_f32_16x16x32_bf16(pa, vf[dn], oacc[dn], 0, 0, 0);
    }
    __syncthreads();
  }

  // epilogue: single cross-lane sum-reduce, normalize, store bf16 token-major
#pragma unroll
  for (int r = 0; r < 4; ++r) {
    float s = lsum[r];
    s += __shfl_xor(s, 1);
    s += __shfl_xor(s, 2);
    s += __shfl_xor(s, 4);
    s += __shfl_xor(s, 8);
    float inv = 1.f / s;
    int tok = tok0 + 4 * (l >> 4) + r;
#pragma unroll
    for (int dn = 0; dn < 4; ++dn)
      ob[(size_t)tok * 1024 + h * 64 + dn * 16 + (l & 15)] = (bf16)(oacc[dn][r] * inv);
  }
}

// ---------------- launch ----------------
extern "C" void kernel_launch(void* const* d_in, const int* in_sizes, int n_in,
                              void* d_out, int out_size, void* d_ws, size_t ws_size,
                              hipStream_t stream) {
  const float* x = (const float*)d_in[0];
  const int* mask = (const int*)d_in[1];
  const float* wq = (const float*)d_in[2];
  const float* bq = (const float*)d_in[3];
  const float* wk = (const float*)d_in[4];
  const float* bk = (const float*)d_in[5];
  const float* wv = (const float*)d_in[6];
  const float* bv = (const float*)d_in[7];
  const float* wo = (const float*)d_in[8];
  const float* bo = (const float*)d_in[9];
  float* out = (float*)d_out;

  char* ws = (char*)d_ws;
  bf16* xb = (bf16*)(ws + (size_t)0);             // 8 MB  [4096][1024]
  bf16* wt = (bf16*)(ws + ((size_t)8 << 20));     // 8 MB  [4096][1024] transposed weights
  bf16* qb = (bf16*)(ws + ((size_t)16 << 20));    // 8 MB  token-major (pre-scaled)
  bf16* kb = (bf16*)(ws + ((size_t)24 << 20));    // 8 MB  token-major
  bf16* vtb = (bf16*)(ws + ((size_t)32 << 20));   // 8 MB  [b][h][d][s]
  bf16* ob = (bf16*)(ws + ((size_t)40 << 20));    // 8 MB  token-major
  unsigned long long* mbits = (unsigned long long*)(ws + ((size_t)48 << 20));  // 1 MB

  cast_x_kernel<<<4096, 256, 0, stream>>>(x, xb);
  transpose_w_kernel<<<dim3(128, 32), 256, 0, stream>>>(wq, wk, wv, wo, wt);
  pack_mask_kernel<<<32768, 256, 0, stream>>>(mask, mbits);
  gemm_qkv<<<dim3(24, 32), 256, 0, stream>>>(xb, wt, bq, bk, bv, qb, kb, vtb);
  attn_kernel<<<dim3(32, NH, BATCH), 256, 0, stream>>>(qb, kb, vtb, mbits, ob);
  gemm_out<<<dim3(16, 64), 256, 0, stream>>>(ob, wt + (size_t)3072 * 1024, bo, out);
}

// Round 7
// 241.991 us; speedup vs baseline: 1.9413x; 1.0548x over previous
//
#include <hip/hip_runtime.h>
#include <hip/hip_bf16.h>
#include <stdint.h>

#define D_MODEL 1024
#define NH 16
#define DK 64
#define SEQ 2048
#define BATCH 2
#define NTOK (BATCH * SEQ)  // 4096

typedef __bf16 bf16;
typedef float f32x4 __attribute__((ext_vector_type(4)));
typedef __bf16 bf16x8 __attribute__((ext_vector_type(8)));
typedef __bf16 bf16x4 __attribute__((ext_vector_type(4)));

// 0.125 (1/sqrt(dk)) * log2(e): folded into Q so attn uses exp2 directly
#define QSCALE 0.18033687932432668f

__device__ __forceinline__ void gload_lds16(const void* g, void* l) {
  __builtin_amdgcn_global_load_lds(
      (const __attribute__((address_space(1))) void*)g,
      (__attribute__((address_space(3))) void*)l, 16, 0, 0);
}

// ---------------- fused prep kernel ----------------
// blocks [0,4096): cast x -> bf16
// blocks [4096,8192): transpose+cast weights -> wt[j][k]
// blocks [8192,40960): pack mask bits
__global__ void prep_kernel(const float* __restrict__ x, bf16* __restrict__ xb,
                            const float* __restrict__ wq, const float* __restrict__ wk,
                            const float* __restrict__ wv, const float* __restrict__ wo,
                            bf16* __restrict__ wt,
                            const int* __restrict__ mask, unsigned long long* __restrict__ bits) {
  __shared__ float tile[32][33];
  const int bx = blockIdx.x;
  const int tid = threadIdx.x;
  if (bx < 4096) {
    int i = bx * 256 + tid;
    float4 v = reinterpret_cast<const float4*>(x)[i];
    bf16x4 o;
    o[0] = (bf16)v.x; o[1] = (bf16)v.y; o[2] = (bf16)v.z; o[3] = (bf16)v.w;
    reinterpret_cast<bf16x4*>(xb)[i] = o;
  } else if (bx < 8192) {
    int blk = bx - 4096;
    const int jt = blk & 127;   // 0..127
    const int kt = blk >> 7;    // 0..31
    const int tx = tid & 31, ty = tid >> 5;  // 32 x 8
    const int j0 = jt * 32;
    const int sel = j0 >> 10;
    const float* w = (sel == 0) ? wq : (sel == 1) ? wk : (sel == 2) ? wv : wo;
    const int jj0 = j0 & 1023;
#pragma unroll
    for (int i = 0; i < 4; ++i)
      tile[ty + i * 8][tx] = w[(size_t)(kt * 32 + ty + i * 8) * 1024 + jj0 + tx];
    __syncthreads();
#pragma unroll
    for (int i = 0; i < 4; ++i)
      wt[(size_t)(j0 + ty + i * 8) * 1024 + kt * 32 + tx] = (bf16)tile[tx][ty + i * 8];
  } else {
    int gt = (bx - 8192) * 256 + tid;
    int wid = gt >> 6;
    int l = gt & 63;
    int m = mask[(size_t)wid * 64 + l];
    unsigned long long b = __ballot(m != 0);
    if (l == 0) bits[wid] = b;
  }
}

// ---------------- QKV GEMM: C = A (MxK) * Bt^T (Bt is NxK row-major) ----------------
// epilogue: q scaled by QSCALE; q/k token-major bf16, v transposed per-head bf16
__global__ __launch_bounds__(256) void gemm_qkv(
    const bf16* __restrict__ A, const bf16* __restrict__ Bt,
    const float* __restrict__ b0, const float* __restrict__ b1, const float* __restrict__ b2,
    bf16* __restrict__ out_q, bf16* __restrict__ out_k, bf16* __restrict__ out_vt) {
  __shared__ __align__(16) bf16 As[128 * 32];
  __shared__ __align__(16) bf16 Bs[128 * 32];
  const int tid = threadIdx.x;
  const int w = tid >> 6, l = tid & 63;
  const int wr = w >> 1, wc = w & 1;
  const int m0 = blockIdx.y * 128, n0 = blockIdx.x * 128;
  f32x4 acc[4][4] = {};
  const int lrow = l >> 2;       // 0..15
  const int lc8 = (l & 3) * 8;   // element col of the 16B chunk
  char* AsB = (char*)As;
  char* BsB = (char*)Bs;

  for (int k0 = 0; k0 < 1024; k0 += 32) {
#pragma unroll
    for (int is = 0; is < 2; ++is) {
      int arow = m0 + is * 64 + w * 16 + lrow;
      gload_lds16(A + (size_t)arow * 1024 + k0 + lc8, AsB + is * 4096 + w * 1024);
      int brow = n0 + is * 64 + w * 16 + lrow;
      gload_lds16(Bt + (size_t)brow * 1024 + k0 + lc8, BsB + is * 4096 + w * 1024);
    }
    __syncthreads();
    bf16x8 af[4], bfr[4];
#pragma unroll
    for (int m = 0; m < 4; ++m)
      af[m] = *reinterpret_cast<const bf16x8*>(As + (wr * 64 + m * 16 + (l & 15)) * 32 + (l >> 4) * 8);
#pragma unroll
    for (int n = 0; n < 4; ++n)
      bfr[n] = *reinterpret_cast<const bf16x8*>(Bs + (wc * 64 + n * 16 + (l & 15)) * 32 + (l >> 4) * 8);
#pragma unroll
    for (int m = 0; m < 4; ++m)
#pragma unroll
      for (int n = 0; n < 4; ++n)
        acc[m][n] = __builtin_amdgcn_mfma_f32_16x16x32_bf16(af[m], bfr[n], acc[m][n], 0, 0, 0);
    __syncthreads();
  }

#pragma unroll
  for (int m = 0; m < 4; ++m) {
    int ib = m0 + wr * 64 + m * 16 + 4 * (l >> 4);
#pragma unroll
    for (int n = 0; n < 4; ++n) {
      int j = n0 + wc * 64 + n * 16 + (l & 15);
      int sel = j >> 10, jj = j & 1023;
      const float* bp = (sel == 0) ? b0 : (sel == 1) ? b1 : b2;
      float bias = bp[jj];
      if (sel == 0) {
#pragma unroll
        for (int r = 0; r < 4; ++r)
          out_q[(size_t)(ib + r) * 1024 + jj] = (bf16)((acc[m][n][r] + bias) * QSCALE);
      } else if (sel == 1) {
#pragma unroll
        for (int r = 0; r < 4; ++r)
          out_k[(size_t)(ib + r) * 1024 + jj] = (bf16)(acc[m][n][r] + bias);
      } else {
        int hh = jj >> 6, dd = jj & 63;
        int bb = ib >> 11, ss = ib & 2047;
        bf16x4 v;
#pragma unroll
        for (int r = 0; r < 4; ++r) v[r] = (bf16)(acc[m][n][r] + bias);
        *reinterpret_cast<bf16x4*>(out_vt + ((size_t)(bb * NH + hh) * DK + dd) * SEQ + ss) = v;
      }
    }
  }
}

// ---------------- out-proj GEMM: 128x64 tile, grid (16,32)=512 blocks (2/CU) ----------------
__global__ __launch_bounds__(256) void gemm_out(
    const bf16* __restrict__ A, const bf16* __restrict__ Bt,
    const float* __restrict__ bias, float* __restrict__ out) {
  __shared__ __align__(16) bf16 As[128 * 32];  // 8KB
  __shared__ __align__(16) bf16 Bs[64 * 32];   // 4KB
  const int tid = threadIdx.x;
  const int w = tid >> 6, l = tid & 63;
  const int wr = w >> 1, wc = w & 1;  // wave owns 64m x 32n
  const int m0 = blockIdx.y * 128, n0 = blockIdx.x * 64;
  f32x4 acc[4][2] = {};
  const int lrow = l >> 2;
  const int lc8 = (l & 3) * 8;
  char* AsB = (char*)As;
  char* BsB = (char*)Bs;

  for (int k0 = 0; k0 < 1024; k0 += 32) {
#pragma unroll
    for (int is = 0; is < 2; ++is) {
      int arow = m0 + is * 64 + w * 16 + lrow;
      gload_lds16(A + (size_t)arow * 1024 + k0 + lc8, AsB + is * 4096 + w * 1024);
    }
    gload_lds16(Bt + (size_t)(n0 + w * 16 + lrow) * 1024 + k0 + lc8, BsB + w * 1024);
    __syncthreads();
    bf16x8 af[4], bfr[2];
#pragma unroll
    for (int m = 0; m < 4; ++m)
      af[m] = *reinterpret_cast<const bf16x8*>(As + (wr * 64 + m * 16 + (l & 15)) * 32 + (l >> 4) * 8);
#pragma unroll
    for (int n = 0; n < 2; ++n)
      bfr[n] = *reinterpret_cast<const bf16x8*>(Bs + (wc * 32 + n * 16 + (l & 15)) * 32 + (l >> 4) * 8);
#pragma unroll
    for (int m = 0; m < 4; ++m)
#pragma unroll
      for (int n = 0; n < 2; ++n)
        acc[m][n] = __builtin_amdgcn_mfma_f32_16x16x32_bf16(af[m], bfr[n], acc[m][n], 0, 0, 0);
    __syncthreads();
  }

#pragma unroll
  for (int m = 0; m < 4; ++m) {
    int ib = m0 + wr * 64 + m * 16 + 4 * (l >> 4);
#pragma unroll
    for (int n = 0; n < 2; ++n) {
      int j = n0 + wc * 32 + n * 16 + (l & 15);
      float bv = bias[j];
#pragma unroll
      for (int r = 0; r < 4; ++r)
        out[(size_t)(ib + r) * 1024 + j] = acc[m][n][r] + bv;
    }
  }
}

// ---------------- flash attention ----------------
// grid: (32 q-tiles of 64, NH, BATCH) = 1024 blocks, block 256 (4 waves x 16 q-rows).
// LDS 40KB -> 4 blocks/CU, 16 waves/CU. Double-buffered K/V: STAGE(kt+1) issued
// before compute(kt); counted vmcnt keeps the prefetch in flight across barriers.
// No-max softmax + per-lane deferred sum: zero cross-lane ops in the K-loop.
__global__ __launch_bounds__(256, 4) void attn_kernel(
    const bf16* __restrict__ qb, const bf16* __restrict__ kb,
    const bf16* __restrict__ vt, const unsigned long long* __restrict__ mbits,
    bf16* __restrict__ ob) {
  __shared__ __align__(16) bf16 Kbuf[2][64 * 64];  // [key][d] swizzled, 16KB
  __shared__ __align__(16) bf16 Vbuf[2][64 * 64];  // [d][key] swizzled, 16KB
  __shared__ __align__(16) bf16 Ps[4][16 * 64];    // per-wave [q][key] swizzled, 8KB
  const int tid = threadIdx.x;
  const int w = tid >> 6, l = tid & 63;
  const int qt = blockIdx.x, h = blockIdx.y, b = blockIdx.z;
  const int q0 = qt * 64;
  const int qrow = q0 + w * 16;
  const int tok0 = b * SEQ + qrow;

  // Q fragments (pre-scaled by QSCALE in GEMM epilogue)
  bf16x8 qf[2];
#pragma unroll
  for (int kk = 0; kk < 2; ++kk)
    qf[kk] = *reinterpret_cast<const bf16x8*>(
        qb + (size_t)(tok0 + (l & 15)) * 1024 + h * 64 + kk * 32 + (l >> 4) * 8);

  float lsum[4] = {0.f, 0.f, 0.f, 0.f};
  f32x4 oacc[4] = {};

  const int swz = ((l & 7) ^ (l >> 3)) * 8;  // pre-swizzled source chunk (elements)
  const bf16* ksrc = kb + (size_t)(b * SEQ) * 1024 + h * 64;
  const bf16* vsrc = vt + (size_t)(b * NH + h) * DK * SEQ;
  const unsigned long long* mrow = mbits + ((size_t)(b * SEQ + qrow + 4 * (l >> 4)) << 5);

  auto STAGE = [&](int buf, int kt) {
    char* KsB = (char*)Kbuf[buf];
    char* VsB = (char*)Vbuf[buf];
#pragma unroll
    for (int i = 0; i < 2; ++i) {
      int row = i * 32 + w * 8 + (l >> 3);
      gload_lds16(ksrc + (size_t)(kt * 64 + row) * 1024 + swz, KsB + i * 4096 + w * 1024);
      gload_lds16(vsrc + (size_t)row * SEQ + kt * 64 + swz, VsB + i * 4096 + w * 1024);
    }
  };

  STAGE(0, 0);
  for (int kt = 0; kt < 32; ++kt) {
    const int cur = kt & 1;
    // mask-word loads FIRST (older than prefetch in vmcnt queue)
    unsigned long long mw[4];
#pragma unroll
    for (int r = 0; r < 4; ++r) mw[r] = mrow[(size_t)(r << 5) + kt];
    __builtin_amdgcn_sched_barrier(0);
    if (kt < 31) {
      STAGE(cur ^ 1, kt + 1);
      __builtin_amdgcn_sched_barrier(0);
      asm volatile("s_waitcnt vmcnt(8)" ::: "memory");  // stage(kt) done; mw+stage(kt+1) in flight
    } else {
      __builtin_amdgcn_sched_barrier(0);
      asm volatile("s_waitcnt vmcnt(4)" ::: "memory");  // stage(31) done; mw in flight
    }
    __builtin_amdgcn_s_barrier();
    __builtin_amdgcn_sched_barrier(0);

    const bf16* Ks = Kbuf[cur];
    const bf16* Vs = Vbuf[cur];

    // S = Q K^T (16 q x 64 keys per wave)
    f32x4 sa[4] = {};
#pragma unroll
    for (int kk = 0; kk < 2; ++kk) {
      bf16x8 kf[4];
      int c = kk * 4 + (l >> 4);
#pragma unroll
      for (int n = 0; n < 4; ++n) {
        int rr = n * 16 + (l & 15);
        kf[n] = *reinterpret_cast<const bf16x8*>(Ks + rr * 64 + ((c ^ (rr & 7)) << 3));
      }
#pragma unroll
      for (int n = 0; n < 4; ++n)
        sa[n] = __builtin_amdgcn_mfma_f32_16x16x32_bf16(qf[kk], kf[n], sa[n], 0, 0, 0);
    }

    // masked no-max softmax: p = mask ? exp2(s) : 0; per-lane partial sums only
#pragma unroll
    for (int r = 0; r < 4; ++r) {
      int prow = 4 * (l >> 4) + r;
      unsigned long long sh = mw[r] >> (l & 15);
      unsigned int blo = (unsigned int)sh, bhi = (unsigned int)(sh >> 32);
      float p0 = (blo & 1u) ? __builtin_amdgcn_exp2f(sa[0][r]) : 0.f;
      float p1 = (blo & 0x10000u) ? __builtin_amdgcn_exp2f(sa[1][r]) : 0.f;
      float p2 = (bhi & 1u) ? __builtin_amdgcn_exp2f(sa[2][r]) : 0.f;
      float p3 = (bhi & 0x10000u) ? __builtin_amdgcn_exp2f(sa[3][r]) : 0.f;
      lsum[r] += (p0 + p1) + (p2 + p3);
      int colb = l & 7;
      int swzr = (prow & 7);
#pragma unroll
      for (int n = 0; n < 4; ++n) {
        int col = n * 16 + (l & 15);
        float p = (n == 0) ? p0 : (n == 1) ? p1 : (n == 2) ? p2 : p3;
        Ps[w][prow * 64 + (((col >> 3) ^ swzr) << 3) + colb] = (bf16)p;
      }
    }

    // O += P * V
#pragma unroll
    for (int kk = 0; kk < 2; ++kk) {
      int c = kk * 4 + (l >> 4);
      bf16x8 pa, vf[4];
      {
        int rr = l & 15;
        pa = *reinterpret_cast<const bf16x8*>(Ps[w] + rr * 64 + ((c ^ (rr & 7)) << 3));
      }
#pragma unroll
      for (int dn = 0; dn < 4; ++dn) {
        int rr = dn * 16 + (l & 15);
        vf[dn] = *reinterpret_cast<const bf16x8*>(Vs + rr * 64 + ((c ^ (rr & 7)) << 3));
      }
#pragma unroll
      for (int dn = 0; dn < 4; ++dn)
        oacc[dn] = __builtin_amdgcn_mfma_f32_16x16x32_bf16(pa, vf[dn], oacc[dn], 0, 0, 0);
    }
    __builtin_amdgcn_sched_barrier(0);
    __builtin_amdgcn_s_barrier();  // all waves done reading buf(kt) before it is re-staged
  }

  // epilogue: single cross-lane sum-reduce, normalize, store bf16 token-major
#pragma unroll
  for (int r = 0; r < 4; ++r) {
    float s = lsum[r];
    s += __shfl_xor(s, 1);
    s += __shfl_xor(s, 2);
    s += __shfl_xor(s, 4);
    s += __shfl_xor(s, 8);
    float inv = 1.f / s;
    int tok = tok0 + 4 * (l >> 4) + r;
#pragma unroll
    for (int dn = 0; dn < 4; ++dn)
      ob[(size_t)tok * 1024 + h * 64 + dn * 16 + (l & 15)] = (bf16)(oacc[dn][r] * inv);
  }
}

// ---------------- launch ----------------
extern "C" void kernel_launch(void* const* d_in, const int* in_sizes, int n_in,
                              void* d_out, int out_size, void* d_ws, size_t ws_size,
                              hipStream_t stream) {
  const float* x = (const float*)d_in[0];
  const int* mask = (const int*)d_in[1];
  const float* wq = (const float*)d_in[2];
  const float* bq = (const float*)d_in[3];
  const float* wk = (const float*)d_in[4];
  const float* bk = (const float*)d_in[5];
  const float* wv = (const float*)d_in[6];
  const float* bv = (const float*)d_in[7];
  const float* wo = (const float*)d_in[8];
  const float* bo = (const float*)d_in[9];
  float* out = (float*)d_out;

  char* ws = (char*)d_ws;
  bf16* xb = (bf16*)(ws + (size_t)0);             // 8 MB  [4096][1024]
  bf16* wt = (bf16*)(ws + ((size_t)8 << 20));     // 8 MB  [4096][1024] transposed weights
  bf16* qb = (bf16*)(ws + ((size_t)16 << 20));    // 8 MB  token-major (pre-scaled)
  bf16* kb = (bf16*)(ws + ((size_t)24 << 20));    // 8 MB  token-major
  bf16* vtb = (bf16*)(ws + ((size_t)32 << 20));   // 8 MB  [b][h][d][s]
  bf16* ob = (bf16*)(ws + ((size_t)40 << 20));    // 8 MB  token-major
  unsigned long long* mbits = (unsigned long long*)(ws + ((size_t)48 << 20));  // 1 MB

  prep_kernel<<<40960, 256, 0, stream>>>(x, xb, wq, wk, wv, wo, wt, mask, mbits);
  gemm_qkv<<<dim3(24, 32), 256, 0, stream>>>(xb, wt, bq, bk, bv, qb, kb, vtb);
  attn_kernel<<<dim3(32, NH, BATCH), 256, 0, stream>>>(qb, kb, vtb, mbits, ob);
  gemm_out<<<dim3(16, 32), 256, 0, stream>>>(ob, wt + (size_t)3072 * 1024, bo, out);
}

// Round 8
// 234.399 us; speedup vs baseline: 2.0042x; 1.0324x over previous
//
#include <hip/hip_runtime.h>
#include <hip/hip_bf16.h>
#include <stdint.h>

#define D_MODEL 1024
#define NH 16
#define DK 64
#define SEQ 2048
#define BATCH 2
#define NTOK (BATCH * SEQ)  // 4096

typedef __bf16 bf16;
typedef float f32x4 __attribute__((ext_vector_type(4)));
typedef __bf16 bf16x8 __attribute__((ext_vector_type(8)));
typedef __bf16 bf16x4 __attribute__((ext_vector_type(4)));
typedef __bf16 bf16x2 __attribute__((ext_vector_type(2)));

// 0.125 (1/sqrt(dk)) * log2(e): folded into Q so attn uses exp2 directly
#define QSCALE 0.18033687932432668f

__device__ __forceinline__ void gload_lds16(const void* g, void* l) {
  __builtin_amdgcn_global_load_lds(
      (const __attribute__((address_space(1))) void*)g,
      (__attribute__((address_space(3))) void*)l, 16, 0, 0);
}

// ---------------- fused prep kernel ----------------
__global__ void prep_kernel(const float* __restrict__ x, bf16* __restrict__ xb,
                            const float* __restrict__ wq, const float* __restrict__ wk,
                            const float* __restrict__ wv, const float* __restrict__ wo,
                            bf16* __restrict__ wt,
                            const int* __restrict__ mask, unsigned long long* __restrict__ bits) {
  __shared__ float tile[32][33];
  const int bx = blockIdx.x;
  const int tid = threadIdx.x;
  if (bx < 4096) {
    int i = bx * 256 + tid;
    float4 v = reinterpret_cast<const float4*>(x)[i];
    bf16x4 o;
    o[0] = (bf16)v.x; o[1] = (bf16)v.y; o[2] = (bf16)v.z; o[3] = (bf16)v.w;
    reinterpret_cast<bf16x4*>(xb)[i] = o;
  } else if (bx < 8192) {
    int blk = bx - 4096;
    const int jt = blk & 127;
    const int kt = blk >> 7;
    const int tx = tid & 31, ty = tid >> 5;
    const int j0 = jt * 32;
    const int sel = j0 >> 10;
    const float* w = (sel == 0) ? wq : (sel == 1) ? wk : (sel == 2) ? wv : wo;
    const int jj0 = j0 & 1023;
#pragma unroll
    for (int i = 0; i < 4; ++i)
      tile[ty + i * 8][tx] = w[(size_t)(kt * 32 + ty + i * 8) * 1024 + jj0 + tx];
    __syncthreads();
#pragma unroll
    for (int i = 0; i < 4; ++i)
      wt[(size_t)(j0 + ty + i * 8) * 1024 + kt * 32 + tx] = (bf16)tile[tx][ty + i * 8];
  } else {
    int gt = (bx - 8192) * 256 + tid;
    int wid = gt >> 6;
    int l = gt & 63;
    int m = mask[(size_t)wid * 64 + l];
    unsigned long long b = __ballot(m != 0);
    if (l == 0) bits[wid] = b;
  }
}

// ---------------- QKV GEMM: 128x128 tile, 2-phase dbuf, XCD swizzle ----------------
__global__ __launch_bounds__(256) void gemm_qkv(
    const bf16* __restrict__ A, const bf16* __restrict__ Bt,
    const float* __restrict__ b0, const float* __restrict__ b1, const float* __restrict__ b2,
    bf16* __restrict__ out_q, bf16* __restrict__ out_k, bf16* __restrict__ out_vt) {
  __shared__ __align__(16) bf16 As[2][128 * 32];
  __shared__ __align__(16) bf16 Bs[2][128 * 32];
  const int tid = threadIdx.x;
  const int w = tid >> 6, l = tid & 63;
  const int wr = w >> 1, wc = w & 1;
  // XCD-bijective swizzle: grid (24,32)=768, 96 blocks/XCD
  int lin = blockIdx.x + 24 * blockIdx.y;
  int nl = (lin & 7) * 96 + (lin >> 3);
  const int m0 = (nl / 24) * 128, n0 = (nl % 24) * 128;
  f32x4 acc[4][4] = {};
  const int lrow = l >> 2;
  const int lc8 = (l & 3) * 8;

  auto STAGE = [&](int buf, int k0) {
    char* AsB = (char*)As[buf];
    char* BsB = (char*)Bs[buf];
#pragma unroll
    for (int is = 0; is < 2; ++is) {
      int arow = m0 + is * 64 + w * 16 + lrow;
      gload_lds16(A + (size_t)arow * 1024 + k0 + lc8, AsB + is * 4096 + w * 1024);
      int brow = n0 + is * 64 + w * 16 + lrow;
      gload_lds16(Bt + (size_t)brow * 1024 + k0 + lc8, BsB + is * 4096 + w * 1024);
    }
  };

  STAGE(0, 0);
  for (int it = 0; it < 32; ++it) {
    const int cur = it & 1;
    if (it < 31) {
      STAGE(cur ^ 1, (it + 1) * 32);
      __builtin_amdgcn_sched_barrier(0);
      asm volatile("s_waitcnt vmcnt(4)" ::: "memory");
    } else {
      __builtin_amdgcn_sched_barrier(0);
      asm volatile("s_waitcnt vmcnt(0)" ::: "memory");
    }
    __builtin_amdgcn_s_barrier();
    __builtin_amdgcn_sched_barrier(0);
    const bf16* Asc = As[cur];
    const bf16* Bsc = Bs[cur];
    bf16x8 af[4], bfr[4];
#pragma unroll
    for (int m = 0; m < 4; ++m)
      af[m] = *reinterpret_cast<const bf16x8*>(Asc + (wr * 64 + m * 16 + (l & 15)) * 32 + (l >> 4) * 8);
#pragma unroll
    for (int n = 0; n < 4; ++n)
      bfr[n] = *reinterpret_cast<const bf16x8*>(Bsc + (wc * 64 + n * 16 + (l & 15)) * 32 + (l >> 4) * 8);
#pragma unroll
    for (int m = 0; m < 4; ++m)
#pragma unroll
      for (int n = 0; n < 4; ++n)
        acc[m][n] = __builtin_amdgcn_mfma_f32_16x16x32_bf16(af[m], bfr[n], acc[m][n], 0, 0, 0);
    __builtin_amdgcn_sched_barrier(0);
    __builtin_amdgcn_s_barrier();
  }

#pragma unroll
  for (int m = 0; m < 4; ++m) {
    int ib = m0 + wr * 64 + m * 16 + 4 * (l >> 4);
#pragma unroll
    for (int n = 0; n < 4; ++n) {
      int j = n0 + wc * 64 + n * 16 + (l & 15);
      int sel = j >> 10, jj = j & 1023;
      const float* bp = (sel == 0) ? b0 : (sel == 1) ? b1 : b2;
      float bias = bp[jj];
      if (sel == 0) {
#pragma unroll
        for (int r = 0; r < 4; ++r)
          out_q[(size_t)(ib + r) * 1024 + jj] = (bf16)((acc[m][n][r] + bias) * QSCALE);
      } else if (sel == 1) {
#pragma unroll
        for (int r = 0; r < 4; ++r)
          out_k[(size_t)(ib + r) * 1024 + jj] = (bf16)(acc[m][n][r] + bias);
      } else {
        int hh = jj >> 6, dd = jj & 63;
        int bb = ib >> 11, ss = ib & 2047;
        bf16x4 v;
#pragma unroll
        for (int r = 0; r < 4; ++r) v[r] = (bf16)(acc[m][n][r] + bias);
        *reinterpret_cast<bf16x4*>(out_vt + ((size_t)(bb * NH + hh) * DK + dd) * SEQ + ss) = v;
      }
    }
  }
}

// ---------------- out-proj GEMM: 128x64 tile, 2-phase dbuf, XCD swizzle ----------------
__global__ __launch_bounds__(256) void gemm_out(
    const bf16* __restrict__ A, const bf16* __restrict__ Bt,
    const float* __restrict__ bias, float* __restrict__ out) {
  __shared__ __align__(16) bf16 As[2][128 * 32];  // 16KB
  __shared__ __align__(16) bf16 Bs[2][64 * 32];   // 8KB
  const int tid = threadIdx.x;
  const int w = tid >> 6, l = tid & 63;
  const int wr = w >> 1, wc = w & 1;
  // grid (16,32)=512, 64 blocks/XCD
  int lin = blockIdx.x + 16 * blockIdx.y;
  int nl = (lin & 7) * 64 + (lin >> 3);
  const int m0 = (nl >> 4) * 128, n0 = (nl & 15) * 64;
  f32x4 acc[4][2] = {};
  const int lrow = l >> 2;
  const int lc8 = (l & 3) * 8;

  auto STAGE = [&](int buf, int k0) {
    char* AsB = (char*)As[buf];
    char* BsB = (char*)Bs[buf];
#pragma unroll
    for (int is = 0; is < 2; ++is) {
      int arow = m0 + is * 64 + w * 16 + lrow;
      gload_lds16(A + (size_t)arow * 1024 + k0 + lc8, AsB + is * 4096 + w * 1024);
    }
    gload_lds16(Bt + (size_t)(n0 + w * 16 + lrow) * 1024 + k0 + lc8, BsB + w * 1024);
  };

  STAGE(0, 0);
  for (int it = 0; it < 32; ++it) {
    const int cur = it & 1;
    if (it < 31) {
      STAGE(cur ^ 1, (it + 1) * 32);
      __builtin_amdgcn_sched_barrier(0);
      asm volatile("s_waitcnt vmcnt(3)" ::: "memory");
    } else {
      __builtin_amdgcn_sched_barrier(0);
      asm volatile("s_waitcnt vmcnt(0)" ::: "memory");
    }
    __builtin_amdgcn_s_barrier();
    __builtin_amdgcn_sched_barrier(0);
    const bf16* Asc = As[cur];
    const bf16* Bsc = Bs[cur];
    bf16x8 af[4], bfr[2];
#pragma unroll
    for (int m = 0; m < 4; ++m)
      af[m] = *reinterpret_cast<const bf16x8*>(Asc + (wr * 64 + m * 16 + (l & 15)) * 32 + (l >> 4) * 8);
#pragma unroll
    for (int n = 0; n < 2; ++n)
      bfr[n] = *reinterpret_cast<const bf16x8*>(Bsc + (wc * 32 + n * 16 + (l & 15)) * 32 + (l >> 4) * 8);
#pragma unroll
    for (int m = 0; m < 4; ++m)
#pragma unroll
      for (int n = 0; n < 2; ++n)
        acc[m][n] = __builtin_amdgcn_mfma_f32_16x16x32_bf16(af[m], bfr[n], acc[m][n], 0, 0, 0);
    __builtin_amdgcn_sched_barrier(0);
    __builtin_amdgcn_s_barrier();
  }

#pragma unroll
  for (int m = 0; m < 4; ++m) {
    int ib = m0 + wr * 64 + m * 16 + 4 * (l >> 4);
#pragma unroll
    for (int n = 0; n < 2; ++n) {
      int j = n0 + wc * 32 + n * 16 + (l & 15);
      float bv = bias[j];
#pragma unroll
      for (int r = 0; r < 4; ++r)
        out[(size_t)(ib + r) * 1024 + j] = acc[m][n][r] + bv;
    }
  }
}

// ---------------- flash attention (swapped QK^T, in-lane softmax rows) ----------------
// grid 1024 blocks (XCD-swizzled), block 256 = 4 waves x 16 q-rows.
// QK^T computed as mfma(K,Q): lane(a=l>>4, c=l&15) holds P[key=16n+4a+r][q=c].
// -> 1 mask load/tile, per-lane scalar lsum (no cross-lane in loop), vectorized P pair-writes.
__global__ __launch_bounds__(256, 4) void attn_kernel(
    const bf16* __restrict__ qb, const bf16* __restrict__ kb,
    const bf16* __restrict__ vt, const unsigned long long* __restrict__ mbits,
    bf16* __restrict__ ob) {
  __shared__ __align__(16) bf16 Kbuf[2][64 * 64];  // [key][d] swizzled, 16KB
  __shared__ __align__(16) bf16 Vbuf[2][64 * 64];  // [d][key] swizzled, 16KB
  __shared__ __align__(16) bf16 Ps[4][16 * 64];    // per-wave [q][key] swizzled, 8KB
  const int tid = threadIdx.x;
  const int w = tid >> 6, l = tid & 63;
  // XCD swizzle: 1024 blocks, 128/XCD
  int lin = blockIdx.x + 32 * blockIdx.y + 512 * blockIdx.z;
  int nl = (lin & 7) * 128 + (lin >> 3);
  const int qt = nl & 31, h = (nl >> 5) & 15, b = nl >> 9;
  const int q0 = qt * 64;
  const int qrow = q0 + w * 16;
  const int tok0 = b * SEQ + qrow;
  const int a = l >> 4, c = l & 15;

  // Q fragments (pre-scaled by QSCALE in GEMM epilogue); used as MFMA B-operand
  bf16x8 qf[2];
#pragma unroll
  for (int kk = 0; kk < 2; ++kk)
    qf[kk] = *reinterpret_cast<const bf16x8*>(
        qb + (size_t)(tok0 + c) * 1024 + h * 64 + kk * 32 + a * 8);

  float lsum = 0.f;
  f32x4 oacc[4] = {};

  const int swz = ((l & 7) ^ (l >> 3)) * 8;  // pre-swizzled source chunk for staging
  const bf16* ksrc = kb + (size_t)(b * SEQ) * 1024 + h * 64;
  const bf16* vsrc = vt + (size_t)(b * NH + h) * DK * SEQ;
  const unsigned long long* mrow = mbits + ((size_t)(b * SEQ + qrow + c) << 5);

  auto STAGE = [&](int buf, int kt) {
    char* KsB = (char*)Kbuf[buf];
    char* VsB = (char*)Vbuf[buf];
#pragma unroll
    for (int i = 0; i < 2; ++i) {
      int row = i * 32 + w * 8 + (l >> 3);
      gload_lds16(ksrc + (size_t)(kt * 64 + row) * 1024 + swz, KsB + i * 4096 + w * 1024);
      gload_lds16(vsrc + (size_t)row * SEQ + kt * 64 + swz, VsB + i * 4096 + w * 1024);
    }
  };

  STAGE(0, 0);
  for (int kt = 0; kt < 32; ++kt) {
    const int cur = kt & 1;
    unsigned long long mw = mrow[kt];  // issued before prefetch: older in vmcnt queue
    __builtin_amdgcn_sched_barrier(0);
    if (kt < 31) {
      STAGE(cur ^ 1, kt + 1);
      __builtin_amdgcn_sched_barrier(0);
      asm volatile("s_waitcnt vmcnt(8)" ::: "memory");  // stage(kt)+mw done
    } else {
      __builtin_amdgcn_sched_barrier(0);
      asm volatile("s_waitcnt vmcnt(0)" ::: "memory");
    }
    __builtin_amdgcn_s_barrier();
    __builtin_amdgcn_sched_barrier(0);

    const bf16* Ks = Kbuf[cur];
    const bf16* Vs = Vbuf[cur];

    // S^T = K Q^T : sa[n][r] = P[key=16n+4a+r][q=qrow+c]
    f32x4 sa[4] = {};
#pragma unroll
    for (int kk = 0; kk < 2; ++kk) {
      bf16x8 kf[4];
      int cc = kk * 4 + a;
#pragma unroll
      for (int n = 0; n < 4; ++n) {
        int rr = n * 16 + c;
        kf[n] = *reinterpret_cast<const bf16x8*>(Ks + rr * 64 + ((cc ^ (rr & 7)) << 3));
      }
#pragma unroll
      for (int n = 0; n < 4; ++n)
        sa[n] = __builtin_amdgcn_mfma_f32_16x16x32_bf16(kf[n], qf[kk], sa[n], 0, 0, 0);
    }

    // masked no-max softmax, per-lane scalar partial sum
    unsigned long long base = mw >> (a * 4);
    float ps[4][4];
#pragma unroll
    for (int n = 0; n < 4; ++n)
#pragma unroll
      for (int r = 0; r < 4; ++r) {
        bool on = (base >> (16 * n + r)) & 1ull;
        float p = on ? __builtin_amdgcn_exp2f(sa[n][r]) : 0.f;
        ps[n][r] = p;
        lsum += p;
      }
    // vectorized pair-writes: P[q=c][key 16n+4a+2pp..+1]
#pragma unroll
    for (int n = 0; n < 4; ++n)
#pragma unroll
      for (int pp = 0; pp < 2; ++pp) {
        int chunk = (2 * n + (a >> 1)) ^ (c & 7);
        bf16x2 v2 = {(bf16)ps[n][2 * pp], (bf16)ps[n][2 * pp + 1]};
        *reinterpret_cast<bf16x2*>(Ps[w] + c * 64 + chunk * 8 + 4 * (a & 1) + 2 * pp) = v2;
      }

    // O += P * V  (pa = A-fragment straight from swizzled Ps)
#pragma unroll
    for (int kk = 0; kk < 2; ++kk) {
      bf16x8 pa = *reinterpret_cast<const bf16x8*>(Ps[w] + c * 64 + (((a + 4 * kk) ^ (c & 7)) << 3));
      bf16x8 vf[4];
#pragma unroll
      for (int dn = 0; dn < 4; ++dn) {
        int rr = dn * 16 + c;
        vf[dn] = *reinterpret_cast<const bf16x8*>(Vs + rr * 64 + (((kk * 4 + a) ^ (rr & 7)) << 3));
      }
#pragma unroll
      for (int dn = 0; dn < 4; ++dn)
        oacc[dn] = __builtin_amdgcn_mfma_f32_16x16x32_bf16(pa, vf[dn], oacc[dn], 0, 0, 0);
    }
    __builtin_amdgcn_sched_barrier(0);
    __builtin_amdgcn_s_barrier();
  }

  // epilogue: reduce lsum across a-groups, redistribute to oacc rows, store
  float s = lsum;
  s += __shfl_xor(s, 16);
  s += __shfl_xor(s, 32);
#pragma unroll
  for (int r = 0; r < 4; ++r) {
    float sr = __shfl(s, 4 * a + r);
    float inv = 1.f / fmaxf(sr, 1e-35f);
    int tok = tok0 + 4 * a + r;
#pragma unroll
    for (int dn = 0; dn < 4; ++dn)
      ob[(size_t)tok * 1024 + h * 64 + dn * 16 + c] = (bf16)(oacc[dn][r] * inv);
  }
}

// ---------------- launch ----------------
extern "C" void kernel_launch(void* const* d_in, const int* in_sizes, int n_in,
                              void* d_out, int out_size, void* d_ws, size_t ws_size,
                              hipStream_t stream) {
  const float* x = (const float*)d_in[0];
  const int* mask = (const int*)d_in[1];
  const float* wq = (const float*)d_in[2];
  const float* bq = (const float*)d_in[3];
  const float* wk = (const float*)d_in[4];
  const float* bk = (const float*)d_in[5];
  const float* wv = (const float*)d_in[6];
  const float* bv = (const float*)d_in[7];
  const float* wo = (const float*)d_in[8];
  const float* bo = (const float*)d_in[9];
  float* out = (float*)d_out;

  char* ws = (char*)d_ws;
  bf16* xb = (bf16*)(ws + (size_t)0);
  bf16* wt = (bf16*)(ws + ((size_t)8 << 20));
  bf16* qb = (bf16*)(ws + ((size_t)16 << 20));
  bf16* kb = (bf16*)(ws + ((size_t)24 << 20));
  bf16* vtb = (bf16*)(ws + ((size_t)32 << 20));
  bf16* ob = (bf16*)(ws + ((size_t)40 << 20));
  unsigned long long* mbits = (unsigned long long*)(ws + ((size_t)48 << 20));

  prep_kernel<<<40960, 256, 0, stream>>>(x, xb, wq, wk, wv, wo, wt, mask, mbits);
  gemm_qkv<<<dim3(24, 32), 256, 0, stream>>>(xb, wt, bq, bk, bv, qb, kb, vtb);
  attn_kernel<<<dim3(32, NH, BATCH), 256, 0, stream>>>(qb, kb, vtb, mbits, ob);
  gemm_out<<<dim3(16, 32), 256, 0, stream>>>(ob, wt + (size_t)3072 * 1024, bo, out);
}